// Round 1
// baseline (373.201 us; speedup 1.0000x reference)
//
#include <hip/hip_runtime.h>
#include <hip/hip_fp16.h>
#include <math.h>

// VolumeCarver: out[r] = sum_i alpha_i * prod_{j=1..i} trans_j  (includes j=i, excludes j=0)
// alpha_i = 1 - exp(-sigmoid(logits[leaf_i]) * delta_i); trans_j = min(1, 1-alpha_j+1e-10).
//
// R6: persistent software-pipelined waves. Each wave owns 8 consecutive 8-ray groups;
// while computing group g it already has group g+1's 16 gathers + tt streams and
// group g+2's leaf streams in flight (~24 VMEM instrs outstanding per wave at all
// times). Grid = 1024 blocks = exactly-resident (4 blocks/CU), so no ramp/tail.

#define NRAYS 262144
#define LEN   128
#define NLEAF 1048576
#define MAXD  1e10f
#define EPSW  1e-10f
#define GPW   8      // groups of 8 rays per wave

typedef float v4f __attribute__((ext_vector_type(4)));
typedef int   v4i __attribute__((ext_vector_type(4)));

__device__ __forceinline__ float fast_sigmoid(float x) {
    return __builtin_amdgcn_rcpf(1.0f + __expf(-x));
}

// 1 - exp(-x), x >= 0. Poly for small x (rel err < 2e-7 for x < 0.1).
__device__ __forceinline__ float omexp(float x) {
    float p = x * (1.0f + x * (-0.5f + x * (0.16666667f - 0.041666668f * x)));
    return (x < 0.1f) ? p : (1.0f - __expf(-x));
}

// Dword-aligned gather of fp16 entry idx from table (2B entries packed in dwords).
__device__ __forceinline__ float tab_gather32(const unsigned int* tb32, int idx) {
    unsigned int v = tb32[idx >> 1];
    unsigned short u = (unsigned short)(v >> ((idx & 1) * 16));
    __half h;
    *(unsigned short*)&h = u;
    return __half2float(h);
}

__global__ __launch_bounds__(256) void sig_kernel(const float* __restrict__ logits,
                                                  __half* __restrict__ tab) {
    int i = blockIdx.x * 256 + threadIdx.x;   // grid = NLEAF/256
    tab[i] = __float2half(fast_sigmoid(logits[i]));
}

template <bool TAB>
__device__ __forceinline__ void do_gather(const void* __restrict__ table,
                                          const v4i lv[4], float op[4][4]) {
    if (TAB) {
        const unsigned int* tb32 = (const unsigned int*)table;
        #pragma unroll
        for (int c = 0; c < 4; ++c) {
            op[c][0] = tab_gather32(tb32, lv[c].x);
            op[c][1] = tab_gather32(tb32, lv[c].y);
            op[c][2] = tab_gather32(tb32, lv[c].z);
            op[c][3] = tab_gather32(tb32, lv[c].w);
        }
    } else {
        const float* lg = (const float*)table;
        #pragma unroll
        for (int c = 0; c < 4; ++c) {
            op[c][0] = fast_sigmoid(lg[lv[c].x]);
            op[c][1] = fast_sigmoid(lg[lv[c].y]);
            op[c][2] = fast_sigmoid(lg[lv[c].z]);
            op[c][3] = fast_sigmoid(lg[lv[c].w]);
        }
    }
}

__device__ __forceinline__ float compute_ray(const v4f tt[4], const float op[4][4],
                                             int lane, int sub, int gbase) {
    // Per-chunk local (P,S) over the lane's 4 consecutive elements.
    float P[4], S[4];
    #pragma unroll
    for (int c = 0; c < 4; ++c) {
        // value of the element AFTER this lane's last one in chunk c:
        //   sub<7 : next lane's tt[c].x
        //   sub==7: chunk c+1's tt.x at group's lane 0 (or MAXD at ray end)
        float nxt_dn = __shfl_down(tt[c].x, 1);
        float nxt_c1 = (c < 3) ? __shfl(tt[(c + 1) & 3].x, gbase) : MAXD;
        float nxt = (sub == 7) ? nxt_c1 : nxt_dn;

        float d0 = tt[c].y - tt[c].x;
        float d1 = tt[c].z - tt[c].y;
        float d2 = tt[c].w - tt[c].z;
        float d3 = nxt - tt[c].w;

        float a0 = omexp(op[c][0] * d0);
        float a1 = omexp(op[c][1] * d1);
        float a2 = omexp(op[c][2] * d2);
        float a3 = omexp(op[c][3] * d3);

        float r0 = fminf(1.0f, 1.0f - a0 + EPSW);
        float r1 = fminf(1.0f, 1.0f - a1 + EPSW);
        float r2 = fminf(1.0f, 1.0f - a2 + EPSW);
        float r3 = fminf(1.0f, 1.0f - a3 + EPSW);
        if (c == 0 && sub == 0) r0 = 1.0f;   // ray's trans[0] excluded everywhere

        float cc = r0;        float ss = a0 * cc;
        cc *= r1;             ss = fmaf(a1, cc, ss);
        cc *= r2;             ss = fmaf(a2, cc, ss);
        cc *= r3;             ss = fmaf(a3, cc, ss);
        P[c] = cc;  S[c] = ss;
    }

    // Ordered butterfly over the 8-lane ray group, all 4 chunks concurrently.
    #pragma unroll
    for (int o = 1; o < 8; o <<= 1) {
        #pragma unroll
        for (int c = 0; c < 4; ++c) {
            float Pp = __shfl_xor(P[c], o);
            float Sp = __shfl_xor(S[c], o);
            S[c] = (lane & o) ? fmaf(Pp, S[c], Sp) : fmaf(P[c], Sp, S[c]);
            P[c] *= Pp;
        }
    }

    // Chain the 4 chunk segments in order.
    float Sr = fmaf(P[2], S[3], S[2]);
    Sr = fmaf(P[1], Sr, S[1]);
    Sr = fmaf(P[0], Sr, S[0]);
    return Sr;
}

// One pipeline step: issue next group's gathers + tt streams and group-after-next's
// leaf streams, THEN compute the current group. IT is compile-time so all buffer
// indices are static (no scratch).
template <bool TAB, int IT>
__device__ __forceinline__ void pipe_step(
    const float* __restrict__ t_stops, const int* __restrict__ leaves,
    const void* __restrict__ table, float* __restrict__ out,
    v4i lv[4], const v4f ttc[4], v4f ttn[4],
    const float opc[4][4], float opn[4][4],
    int eb0, int w, int lane, int sub, int gbase)
{
    if (IT + 1 < GPW) {
        do_gather<TAB>(table, lv, opn);            // group IT+1 (lv holds its indices)
        #pragma unroll
        for (int c = 0; c < 4; ++c)
            ttn[c] = __builtin_nontemporal_load(
                (const v4f*)(t_stops + eb0 + (IT + 1) * 1024 + c * 32));
        if (IT + 2 < GPW) {
            // WAR on lv is safe: VMEM reads addresses at issue.
            #pragma unroll
            for (int c = 0; c < 4; ++c)
                lv[c] = __builtin_nontemporal_load(
                    (const v4i*)(leaves + eb0 + (IT + 2) * 1024 + c * 32));
        }
    }
    float Sr = compute_ray(ttc, opc, lane, sub, gbase);
    if (sub == 0)
        out[(w * GPW + IT) * 8 + (lane >> 3)] = Sr;
}

template <bool TAB>
__global__ __launch_bounds__(256) void vc_kernel(
    const float* __restrict__ t_stops,   // [R, L]
    const int*   __restrict__ leaves,    // [R, L]
    const void*  __restrict__ table,     // fp16 sigmoid table (TAB) or raw f32 logits
    float*       __restrict__ out)       // [R]
{
    const int lane  = threadIdx.x & 63;
    const int sub   = lane & 7;                      // 8 lanes per ray
    const int gbase = lane & 56;                     // first lane of this ray group
    const int w     = blockIdx.x * 4 + (threadIdx.x >> 6);   // wave id, 0..4095

    // element base for this wave's group 0 (fits in int: max ~33.5M)
    const int eb0 = (w * GPW * 8 + (lane >> 3)) * LEN + sub * 4;

    v4i  lv[4];          // leaf indices for the NEXT group to be gathered
    v4f  tt[2][4];       // double-buffered t_stops
    float op[2][4][4];   // double-buffered gathered opacities

    // Prologue: group 0 lv+tt, gather group 0, prefetch group 1 lv.
    #pragma unroll
    for (int c = 0; c < 4; ++c)
        lv[c] = __builtin_nontemporal_load((const v4i*)(leaves + eb0 + c * 32));
    #pragma unroll
    for (int c = 0; c < 4; ++c)
        tt[0][c] = __builtin_nontemporal_load((const v4f*)(t_stops + eb0 + c * 32));
    do_gather<TAB>(table, lv, op[0]);
    #pragma unroll
    for (int c = 0; c < 4; ++c)
        lv[c] = __builtin_nontemporal_load((const v4i*)(leaves + eb0 + 1024 + c * 32));

    // 8 fully-unrolled pipeline steps, ping-ponging the buffers.
    pipe_step<TAB, 0>(t_stops, leaves, table, out, lv, tt[0], tt[1], op[0], op[1], eb0, w, lane, sub, gbase);
    pipe_step<TAB, 1>(t_stops, leaves, table, out, lv, tt[1], tt[0], op[1], op[0], eb0, w, lane, sub, gbase);
    pipe_step<TAB, 2>(t_stops, leaves, table, out, lv, tt[0], tt[1], op[0], op[1], eb0, w, lane, sub, gbase);
    pipe_step<TAB, 3>(t_stops, leaves, table, out, lv, tt[1], tt[0], op[1], op[0], eb0, w, lane, sub, gbase);
    pipe_step<TAB, 4>(t_stops, leaves, table, out, lv, tt[0], tt[1], op[0], op[1], eb0, w, lane, sub, gbase);
    pipe_step<TAB, 5>(t_stops, leaves, table, out, lv, tt[1], tt[0], op[1], op[0], eb0, w, lane, sub, gbase);
    pipe_step<TAB, 6>(t_stops, leaves, table, out, lv, tt[0], tt[1], op[0], op[1], eb0, w, lane, sub, gbase);
    pipe_step<TAB, 7>(t_stops, leaves, table, out, lv, tt[1], tt[0], op[1], op[0], eb0, w, lane, sub, gbase);
}

extern "C" void kernel_launch(void* const* d_in, const int* in_sizes, int n_in,
                              void* d_out, int out_size, void* d_ws, size_t ws_size,
                              hipStream_t stream) {
    const float* t_stops = (const float*)d_in[0];
    const int*   leaves  = (const int*)d_in[1];
    const float* logits  = (const float*)d_in[2];
    float*       out     = (float*)d_out;

    // 256 rays per block (4 waves x 8 groups x 8 rays) -> 1024 blocks (4/CU).
    if (ws_size >= NLEAF * sizeof(__half)) {
        sig_kernel<<<NLEAF / 256, 256, 0, stream>>>(logits, (__half*)d_ws);
        vc_kernel<true><<<NRAYS / 256, 256, 0, stream>>>(t_stops, leaves, d_ws, out);
    } else {
        vc_kernel<false><<<NRAYS / 256, 256, 0, stream>>>(t_stops, leaves, logits, out);
    }
}

// Round 2
// 368.357 us; speedup vs baseline: 1.0132x; 1.0132x over previous
//
#include <hip/hip_runtime.h>
#include <hip/hip_fp16.h>
#include <math.h>

// VolumeCarver: out[r] = sum_i alpha_i * prod_{j=1..i} trans_j  (includes j=i, excludes j=0)
// alpha_i = 1 - exp(-sigmoid(logits[leaf_i]) * delta_i); trans_j = min(1, 1-alpha_j+1e-10).
//
// R7: R5 structure (wave = 8 rays x 8 lanes, 16 gathers in flight/lane, 66% occupancy)
// with the table gathers switched to agent-scope loads (global_load_dword sc0):
// bypass the 32KB L1 that ~98% of gathers miss anyway. Removes per-CU MSHR
// occupancy and the 64B-line fill amplification (64B fetched per 4B used) on the
// L1<-L2 path. R6 established the limiter is per-CU gather-path serialization,
// not wave-level MLP.

#define NRAYS 262144
#define LEN   128
#define NLEAF 1048576
#define MAXD  1e10f
#define EPSW  1e-10f

typedef float v4f __attribute__((ext_vector_type(4)));
typedef int   v4i __attribute__((ext_vector_type(4)));

__device__ __forceinline__ float fast_sigmoid(float x) {
    return __builtin_amdgcn_rcpf(1.0f + __expf(-x));
}

// 1 - exp(-x), x >= 0. Poly for small x (rel err < 2e-7 for x < 0.1).
__device__ __forceinline__ float omexp(float x) {
    float p = x * (1.0f + x * (-0.5f + x * (0.16666667f - 0.041666668f * x)));
    return (x < 0.1f) ? p : (1.0f - __expf(-x));
}

// Dword-aligned gather of fp16 entry idx from table (2B entries packed in dwords).
// Agent-scope relaxed load -> global_load_dword sc0: bypasses L1 (no tag lookup,
// no MSHR, no 64B line fill) and reads the dword straight from L2.
__device__ __forceinline__ float tab_gather32(const unsigned int* tb32, int idx) {
    unsigned int v = __hip_atomic_load(tb32 + (idx >> 1),
                                       __ATOMIC_RELAXED, __HIP_MEMORY_SCOPE_AGENT);
    unsigned short u = (unsigned short)(v >> ((idx & 1) * 16));
    __half h;
    *(unsigned short*)&h = u;
    return __half2float(h);
}

__global__ __launch_bounds__(256) void sig_kernel(const float* __restrict__ logits,
                                                  __half* __restrict__ tab) {
    int i = blockIdx.x * 256 + threadIdx.x;   // grid = NLEAF/256
    tab[i] = __float2half(fast_sigmoid(logits[i]));
}

template <bool TAB>
__global__ __launch_bounds__(256) void vc_kernel(
    const float* __restrict__ t_stops,   // [R, L]
    const int*   __restrict__ leaves,    // [R, L]
    const void*  __restrict__ table,     // fp16 sigmoid table (TAB) or raw f32 logits
    float*       __restrict__ out)       // [R]
{
    const int lane = threadIdx.x & 63;
    const int wid  = blockIdx.x * 4 + (threadIdx.x >> 6);
    const int ray  = wid * 8 + (lane >> 3);          // 8 rays per wave
    const int sub  = lane & 7;                       // 8 lanes per ray
    const int gbase = lane & 56;                     // first lane of this ray group

    // chunk c covers elements [c*32 + sub*4 .. +3] of the ray (c = 0..3)
    const long long rb = (long long)ray * LEN + sub * 4;

    v4i lv[4];
    v4f tt[4];
    #pragma unroll
    for (int c = 0; c < 4; ++c)
        lv[c] = __builtin_nontemporal_load((const v4i*)(leaves + rb + c * 32));
    #pragma unroll
    for (int c = 0; c < 4; ++c)
        tt[c] = __builtin_nontemporal_load((const v4f*)(t_stops + rb + c * 32));

    // 16 independent gathers issued back-to-back.
    float op[4][4];
    if (TAB) {
        const unsigned int* tb32 = (const unsigned int*)table;
        #pragma unroll
        for (int c = 0; c < 4; ++c) {
            op[c][0] = tab_gather32(tb32, lv[c].x);
            op[c][1] = tab_gather32(tb32, lv[c].y);
            op[c][2] = tab_gather32(tb32, lv[c].z);
            op[c][3] = tab_gather32(tb32, lv[c].w);
        }
    } else {
        const float* lg = (const float*)table;
        #pragma unroll
        for (int c = 0; c < 4; ++c) {
            op[c][0] = fast_sigmoid(lg[lv[c].x]);
            op[c][1] = fast_sigmoid(lg[lv[c].y]);
            op[c][2] = fast_sigmoid(lg[lv[c].z]);
            op[c][3] = fast_sigmoid(lg[lv[c].w]);
        }
    }

    // Per-chunk local (P,S) over the lane's 4 consecutive elements.
    float P[4], S[4];
    #pragma unroll
    for (int c = 0; c < 4; ++c) {
        // value of the element AFTER this lane's last one in chunk c:
        //   sub<7 : next lane's tt[c].x
        //   sub==7: chunk c+1's tt.x at group's lane 0 (or MAXD at ray end)
        float nxt_dn = __shfl_down(tt[c].x, 1);
        float nxt_c1 = (c < 3) ? __shfl(tt[(c + 1) & 3].x, gbase) : MAXD;
        float nxt = (sub == 7) ? nxt_c1 : nxt_dn;

        float d0 = tt[c].y - tt[c].x;
        float d1 = tt[c].z - tt[c].y;
        float d2 = tt[c].w - tt[c].z;
        float d3 = nxt - tt[c].w;

        float a0 = omexp(op[c][0] * d0);
        float a1 = omexp(op[c][1] * d1);
        float a2 = omexp(op[c][2] * d2);
        float a3 = omexp(op[c][3] * d3);

        float r0 = fminf(1.0f, 1.0f - a0 + EPSW);
        float r1 = fminf(1.0f, 1.0f - a1 + EPSW);
        float r2 = fminf(1.0f, 1.0f - a2 + EPSW);
        float r3 = fminf(1.0f, 1.0f - a3 + EPSW);
        if (c == 0 && sub == 0) r0 = 1.0f;   // ray's trans[0] excluded everywhere

        float cc = r0;        float ss = a0 * cc;
        cc *= r1;             ss = fmaf(a1, cc, ss);
        cc *= r2;             ss = fmaf(a2, cc, ss);
        cc *= r3;             ss = fmaf(a3, cc, ss);
        P[c] = cc;  S[c] = ss;
    }

    // Ordered butterfly over the 8-lane ray group, all 4 chunks concurrently.
    #pragma unroll
    for (int o = 1; o < 8; o <<= 1) {
        #pragma unroll
        for (int c = 0; c < 4; ++c) {
            float Pp = __shfl_xor(P[c], o);
            float Sp = __shfl_xor(S[c], o);
            S[c] = (lane & o) ? fmaf(Pp, S[c], Sp) : fmaf(P[c], Sp, S[c]);
            P[c] *= Pp;
        }
    }

    // Chain the 4 chunk segments in order.
    float Sr = fmaf(P[2], S[3], S[2]);
    Sr = fmaf(P[1], Sr, S[1]);
    Sr = fmaf(P[0], Sr, S[0]);

    if (sub == 0)
        out[ray] = Sr;
}

extern "C" void kernel_launch(void* const* d_in, const int* in_sizes, int n_in,
                              void* d_out, int out_size, void* d_ws, size_t ws_size,
                              hipStream_t stream) {
    const float* t_stops = (const float*)d_in[0];
    const int*   leaves  = (const int*)d_in[1];
    const float* logits  = (const float*)d_in[2];
    float*       out     = (float*)d_out;

    if (ws_size >= NLEAF * sizeof(__half)) {
        sig_kernel<<<NLEAF / 256, 256, 0, stream>>>(logits, (__half*)d_ws);
        // 32 rays per 256-thread block (8 rays per wave)
        vc_kernel<true><<<NRAYS / 32, 256, 0, stream>>>(t_stops, leaves, d_ws, out);
    } else {
        vc_kernel<false><<<NRAYS / 32, 256, 0, stream>>>(t_stops, leaves, logits, out);
    }
}

// Round 3
// 367.910 us; speedup vs baseline: 1.0144x; 1.0012x over previous
//
#include <hip/hip_runtime.h>
#include <hip/hip_fp16.h>
#include <math.h>

// VolumeCarver: out[r] = sum_i alpha_i * prod_{j=1..i} trans_j  (includes j=i, excludes j=0)
// alpha_i = 1 - exp(-sigmoid(logits[leaf_i]) * delta_i); trans_j = min(1, 1-alpha_j+1e-10).
//
// R8: vc_kernel is pinned at the divergent-gather roofline (33.5M random requests
// at ~3 cy/request/CU -- R5/R6/R7 all land 164-168us across structurally different
// schedules). This round attacks the OTHER dispatch: sig_kernel (fp16 sigmoid table
// build) was scalar 1-elem/thread (~18us for 6MB of traffic). Vectorized to
// 8 elem/thread: 2x float4 loads + 1x 16B short8 store, 512 blocks.

#define NRAYS 262144
#define LEN   128
#define NLEAF 1048576
#define MAXD  1e10f
#define EPSW  1e-10f

typedef float v4f __attribute__((ext_vector_type(4)));
typedef int   v4i __attribute__((ext_vector_type(4)));
typedef short v8s __attribute__((ext_vector_type(8)));

__device__ __forceinline__ float fast_sigmoid(float x) {
    return __builtin_amdgcn_rcpf(1.0f + __expf(-x));
}

// 1 - exp(-x), x >= 0. Poly for small x (rel err < 2e-7 for x < 0.1).
__device__ __forceinline__ float omexp(float x) {
    float p = x * (1.0f + x * (-0.5f + x * (0.16666667f - 0.041666668f * x)));
    return (x < 0.1f) ? p : (1.0f - __expf(-x));
}

// Dword-aligned gather of fp16 entry idx from table (2B entries packed in dwords).
__device__ __forceinline__ float tab_gather32(const unsigned int* tb32, int idx) {
    unsigned int v = tb32[idx >> 1];
    unsigned short u = (unsigned short)(v >> ((idx & 1) * 16));
    __half h;
    *(unsigned short*)&h = u;
    return __half2float(h);
}

__device__ __forceinline__ short half_bits(float x) {
    __half h = __float2half(x);
    return *(short*)&h;
}

// 8 elements per thread: 2x float4 load, 1x 16B store. grid = NLEAF/2048 = 512.
__global__ __launch_bounds__(256) void sig_kernel(const float* __restrict__ logits,
                                                  __half* __restrict__ tab) {
    int i = (blockIdx.x * 256 + threadIdx.x) * 8;
    v4f a = *(const v4f*)(logits + i);
    v4f b = *(const v4f*)(logits + i + 4);
    v8s r;
    r[0] = half_bits(fast_sigmoid(a.x));
    r[1] = half_bits(fast_sigmoid(a.y));
    r[2] = half_bits(fast_sigmoid(a.z));
    r[3] = half_bits(fast_sigmoid(a.w));
    r[4] = half_bits(fast_sigmoid(b.x));
    r[5] = half_bits(fast_sigmoid(b.y));
    r[6] = half_bits(fast_sigmoid(b.z));
    r[7] = half_bits(fast_sigmoid(b.w));
    *(v8s*)((short*)tab + i) = r;
}

template <bool TAB>
__global__ __launch_bounds__(256) void vc_kernel(
    const float* __restrict__ t_stops,   // [R, L]
    const int*   __restrict__ leaves,    // [R, L]
    const void*  __restrict__ table,     // fp16 sigmoid table (TAB) or raw f32 logits
    float*       __restrict__ out)       // [R]
{
    const int lane = threadIdx.x & 63;
    const int wid  = blockIdx.x * 4 + (threadIdx.x >> 6);
    const int ray  = wid * 8 + (lane >> 3);          // 8 rays per wave
    const int sub  = lane & 7;                       // 8 lanes per ray
    const int gbase = lane & 56;                     // first lane of this ray group

    // chunk c covers elements [c*32 + sub*4 .. +3] of the ray (c = 0..3)
    const long long rb = (long long)ray * LEN + sub * 4;

    v4i lv[4];
    v4f tt[4];
    #pragma unroll
    for (int c = 0; c < 4; ++c)
        lv[c] = __builtin_nontemporal_load((const v4i*)(leaves + rb + c * 32));
    #pragma unroll
    for (int c = 0; c < 4; ++c)
        tt[c] = __builtin_nontemporal_load((const v4f*)(t_stops + rb + c * 32));

    // 16 independent gathers issued back-to-back.
    float op[4][4];
    if (TAB) {
        const unsigned int* tb32 = (const unsigned int*)table;
        #pragma unroll
        for (int c = 0; c < 4; ++c) {
            op[c][0] = tab_gather32(tb32, lv[c].x);
            op[c][1] = tab_gather32(tb32, lv[c].y);
            op[c][2] = tab_gather32(tb32, lv[c].z);
            op[c][3] = tab_gather32(tb32, lv[c].w);
        }
    } else {
        const float* lg = (const float*)table;
        #pragma unroll
        for (int c = 0; c < 4; ++c) {
            op[c][0] = fast_sigmoid(lg[lv[c].x]);
            op[c][1] = fast_sigmoid(lg[lv[c].y]);
            op[c][2] = fast_sigmoid(lg[lv[c].z]);
            op[c][3] = fast_sigmoid(lg[lv[c].w]);
        }
    }

    // Per-chunk local (P,S) over the lane's 4 consecutive elements.
    float P[4], S[4];
    #pragma unroll
    for (int c = 0; c < 4; ++c) {
        // value of the element AFTER this lane's last one in chunk c:
        //   sub<7 : next lane's tt[c].x
        //   sub==7: chunk c+1's tt.x at group's lane 0 (or MAXD at ray end)
        float nxt_dn = __shfl_down(tt[c].x, 1);
        float nxt_c1 = (c < 3) ? __shfl(tt[(c + 1) & 3].x, gbase) : MAXD;
        float nxt = (sub == 7) ? nxt_c1 : nxt_dn;

        float d0 = tt[c].y - tt[c].x;
        float d1 = tt[c].z - tt[c].y;
        float d2 = tt[c].w - tt[c].z;
        float d3 = nxt - tt[c].w;

        float a0 = omexp(op[c][0] * d0);
        float a1 = omexp(op[c][1] * d1);
        float a2 = omexp(op[c][2] * d2);
        float a3 = omexp(op[c][3] * d3);

        float r0 = fminf(1.0f, 1.0f - a0 + EPSW);
        float r1 = fminf(1.0f, 1.0f - a1 + EPSW);
        float r2 = fminf(1.0f, 1.0f - a2 + EPSW);
        float r3 = fminf(1.0f, 1.0f - a3 + EPSW);
        if (c == 0 && sub == 0) r0 = 1.0f;   // ray's trans[0] excluded everywhere

        float cc = r0;        float ss = a0 * cc;
        cc *= r1;             ss = fmaf(a1, cc, ss);
        cc *= r2;             ss = fmaf(a2, cc, ss);
        cc *= r3;             ss = fmaf(a3, cc, ss);
        P[c] = cc;  S[c] = ss;
    }

    // Ordered butterfly over the 8-lane ray group, all 4 chunks concurrently.
    #pragma unroll
    for (int o = 1; o < 8; o <<= 1) {
        #pragma unroll
        for (int c = 0; c < 4; ++c) {
            float Pp = __shfl_xor(P[c], o);
            float Sp = __shfl_xor(S[c], o);
            S[c] = (lane & o) ? fmaf(Pp, S[c], Sp) : fmaf(P[c], Sp, S[c]);
            P[c] *= Pp;
        }
    }

    // Chain the 4 chunk segments in order.
    float Sr = fmaf(P[2], S[3], S[2]);
    Sr = fmaf(P[1], Sr, S[1]);
    Sr = fmaf(P[0], Sr, S[0]);

    if (sub == 0)
        out[ray] = Sr;
}

extern "C" void kernel_launch(void* const* d_in, const int* in_sizes, int n_in,
                              void* d_out, int out_size, void* d_ws, size_t ws_size,
                              hipStream_t stream) {
    const float* t_stops = (const float*)d_in[0];
    const int*   leaves  = (const int*)d_in[1];
    const float* logits  = (const float*)d_in[2];
    float*       out     = (float*)d_out;

    if (ws_size >= NLEAF * sizeof(__half)) {
        sig_kernel<<<NLEAF / 2048, 256, 0, stream>>>(logits, (__half*)d_ws);
        // 32 rays per 256-thread block (8 rays per wave)
        vc_kernel<true><<<NRAYS / 32, 256, 0, stream>>>(t_stops, leaves, d_ws, out);
    } else {
        vc_kernel<false><<<NRAYS / 32, 256, 0, stream>>>(t_stops, leaves, logits, out);
    }
}